// Round 1
// baseline (2828.045 us; speedup 1.0000x reference)
//
#include <hip/hip_runtime.h>

// ---------------- constants ----------------
#define HDIM 1024
#define BB 8
#define SS 1024
#define NHEAD 16
#define PFF 4096
#define NLAYER 6
#define MM (BB*SS)   // 8192 rows

typedef __attribute__((ext_vector_type(8))) short bf16x8_t;
typedef __attribute__((ext_vector_type(4))) float f32x4_t;

static __device__ __forceinline__ unsigned short f2b(float f) {
  unsigned int u = __float_as_uint(f);
  u += 0x7fffu + ((u >> 16) & 1u);      // RNE
  return (unsigned short)(u >> 16);
}

static __device__ __forceinline__ void gload16(const void* g, void* l) {
  __builtin_amdgcn_global_load_lds((__attribute__((address_space(1))) void*)g,
                                   (__attribute__((address_space(3))) void*)l, 16, 0, 0);
}

// ---------------- fp32 -> bf16 convert ----------------
__global__ __launch_bounds__(256) void cvt_bf16(const float* __restrict__ in,
                                                unsigned short* __restrict__ o, int n4) {
  const int i = blockIdx.x * 256 + threadIdx.x;
  if (i < n4) {
    const float4 v = ((const float4*)in)[i];
    ushort4 ob = { f2b(v.x), f2b(v.y), f2b(v.z), f2b(v.w) };
    ((ushort4*)o)[i] = ob;
  }
}

// ---------------- transpose fp32 [R][C] -> bf16 [C][R] ----------------
__global__ __launch_bounds__(256) void transpose_bf16(const float* __restrict__ in,
                                                      unsigned short* __restrict__ outT,
                                                      int R, int C) {
  __shared__ float tile[32][33];
  const int c0 = blockIdx.x * 32, r0 = blockIdx.y * 32;
  const int tx = threadIdx.x, ty = threadIdx.y;   // (32,8)
#pragma unroll
  for (int i = 0; i < 4; ++i)
    tile[ty + 8*i][tx] = in[(size_t)(r0 + ty + 8*i) * C + c0 + tx];
  __syncthreads();
#pragma unroll
  for (int i = 0; i < 4; ++i)
    outT[(size_t)(c0 + ty + 8*i) * R + r0 + tx] = f2b(tile[tx][ty + 8*i]);
}

// ---------------- GEMM: A[M][K] bf16 @ Bt[N][K] bf16 -> out[M][N] ----------------
// 128x128 tile, BK=64, 4 waves (2x2), 16x16x32 bf16 MFMA, global_load_lds staging
// with XOR-swizzled source (byte ^= (row&7)<<4) matched by swizzled ds_read_b128.
template<bool BIAS, bool RELU, bool RESID, bool EMB, bool WF32, bool WBF16>
__global__ __launch_bounds__(256) void gemm_bt(
    const unsigned short* __restrict__ A,
    const unsigned short* __restrict__ Bt,
    const float* __restrict__ bias,
    const float* __restrict__ resid,
    const float* __restrict__ pos,
    float* __restrict__ outf,
    unsigned short* __restrict__ outb,
    int M, int N, int K) {
  __shared__ __align__(1024) char smem[32768];   // A 16KB | B 16KB
  const int t = threadIdx.x;
  const int lane = t & 63;
  const int w = t >> 6;
  const int wr = w >> 1, wc = w & 1;
  const int m0 = blockIdx.y * 128;
  const int n0 = blockIdx.x * 128;

  const f32x4_t z = {0.f, 0.f, 0.f, 0.f};
  f32x4_t acc[4][4];
#pragma unroll
  for (int i = 0; i < 4; ++i)
#pragma unroll
    for (int j = 0; j < 4; ++j) acc[i][j] = z;

  const int nkt = K >> 6;
  for (int kt = 0; kt < nkt; ++kt) {
#pragma unroll
    for (int i = 0; i < 4; ++i) {
      const int chunk = i * 4 + w;                 // wave-uniform 1KB chunk
      const int byteoff = chunk * 1024 + lane * 16;
      const int row = byteoff >> 7;                // tile row (0..127)
      const int scb = (byteoff & 127) ^ ((row & 7) << 4);
      gload16((const char*)A  + ((size_t)(m0 + row) * K + (kt << 6)) * 2 + scb,
              smem + chunk * 1024);
      gload16((const char*)Bt + ((size_t)(n0 + row) * K + (kt << 6)) * 2 + scb,
              smem + 16384 + chunk * 1024);
    }
    __syncthreads();
#pragma unroll
    for (int ks = 0; ks < 2; ++ks) {
      bf16x8_t af[4], bfv[4];
      const int cb = ks * 64 + ((lane >> 4) << 4);
#pragma unroll
      for (int i = 0; i < 4; ++i) {
        const int ra = wr * 64 + i * 16 + (lane & 15);
        af[i]  = *(const bf16x8_t*)(smem + ra * 128 + (cb ^ ((ra & 7) << 4)));
        const int rb = wc * 64 + i * 16 + (lane & 15);
        bfv[i] = *(const bf16x8_t*)(smem + 16384 + rb * 128 + (cb ^ ((rb & 7) << 4)));
      }
#pragma unroll
      for (int i = 0; i < 4; ++i)
#pragma unroll
        for (int j = 0; j < 4; ++j)
          acc[i][j] = __builtin_amdgcn_mfma_f32_16x16x32_bf16(af[i], bfv[j], acc[i][j], 0, 0, 0);
    }
    __syncthreads();
  }

  // epilogue: C/D layout col=lane&15, row=(lane>>4)*4+r
#pragma unroll
  for (int i = 0; i < 4; ++i) {
    const int rbase = m0 + wr * 64 + i * 16 + ((lane >> 4) << 2);
#pragma unroll
    for (int j = 0; j < 4; ++j) {
      const int cc = n0 + wc * 64 + j * 16 + (lane & 15);
      float bv = 0.f;
      if (BIAS) bv = bias[cc];
#pragma unroll
      for (int r = 0; r < 4; ++r) {
        const int row = rbase + r;
        float v = acc[i][j][r] + bv;
        if (EMB)  v = v * 32.f + pos[(size_t)(row & (SS - 1)) * N + cc];
        if (RELU) v = fmaxf(v, 0.f);
        if (RESID) v += resid[(size_t)row * N + cc];
        if (WF32)  outf[(size_t)row * N + cc] = v;
        if (WBF16) outb[(size_t)row * N + cc] = f2b(v);
      }
    }
  }
}

// ---------------- flash attention ----------------
// grid (S/128, B*NH), 256 threads. Wave w owns 32 q-rows. KV tiles of 64.
// scores = (Q.K^T)/32, online softmax, PV accumulated in fp32.
__global__ __launch_bounds__(256) void attn_kernel(
    const unsigned short* Q,                 // no __restrict__: may alias O
    const unsigned short* __restrict__ Kb,
    const unsigned short* __restrict__ V,
    unsigned short* O) {
  __shared__ __align__(1024) char smem[8192 + 9216 + 4 * 4608];
  char* k_lds  = smem;                 // [64][64] bf16, XOR-swizzled
  char* vt_lds = smem + 8192;          // [64 d][72 k] bf16 (padded)
  const int t = threadIdx.x, lane = t & 63, w = t >> 6;
  char* p_lds = smem + 8192 + 9216 + w * 4608;  // per-wave [32][72] bf16

  const int bh = blockIdx.y;
  const int b = bh >> 4, h = bh & 15;
  const size_t rowb = (size_t)b << 10;
  const int colb = h << 6;
  const int q0 = blockIdx.x * 128 + w * 32;

  // Q fragments in registers (reused across all 16 KV tiles)
  bf16x8_t qf[2][2];
#pragma unroll
  for (int i = 0; i < 2; ++i)
#pragma unroll
    for (int ks = 0; ks < 2; ++ks) {
      const int qr = q0 + i * 16 + (lane & 15);
      const int cc = colb + ks * 32 + ((lane >> 4) << 3);
      qf[i][ks] = *(const bf16x8_t*)(Q + (rowb + qr) * HDIM + cc);
    }

  const f32x4_t z = {0.f, 0.f, 0.f, 0.f};
  f32x4_t o_acc[2][4];
  float m_run[2][4], l_run[2][4];
#pragma unroll
  for (int i = 0; i < 2; ++i)
#pragma unroll
    for (int jd = 0; jd < 4; ++jd) o_acc[i][jd] = z;
#pragma unroll
  for (int i = 0; i < 2; ++i)
#pragma unroll
    for (int r = 0; r < 4; ++r) { m_run[i][r] = -1e30f; l_run[i][r] = 0.f; }

  for (int kt = 0; kt < 16; ++kt) {
    __syncthreads();   // prev tile consumed
    // stage K tile (swizzled source -> linear LDS dest)
#pragma unroll
    for (int i = 0; i < 2; ++i) {
      const int chunk = i * 4 + w;
      const int byteoff = chunk * 1024 + lane * 16;
      const int row = byteoff >> 7;
      const int scb = (byteoff & 127) ^ ((row & 7) << 4);
      gload16((const char*)Kb + ((rowb + kt * 64 + row) * HDIM + colb) * 2 + scb,
              k_lds + chunk * 1024);
    }
    // stage V transposed: wave w gathers k-rows [w*16, w*16+16), lane = d column
    {
      const int d = lane;
      const int kb0 = w * 16;
      const unsigned short* vp = V + (rowb + kt * 64 + kb0) * HDIM + colb + d;
      bf16x8_t v0, v1;
#pragma unroll
      for (int kk = 0; kk < 8; ++kk) v0[kk] = (short)vp[(size_t)kk * HDIM];
#pragma unroll
      for (int kk = 0; kk < 8; ++kk) v1[kk] = (short)vp[(size_t)(kk + 8) * HDIM];
      *(bf16x8_t*)(vt_lds + d * 144 + kb0 * 2)      = v0;
      *(bf16x8_t*)(vt_lds + d * 144 + kb0 * 2 + 16) = v1;
    }
    __syncthreads();

    // QK^T
    f32x4_t s[2][4];
#pragma unroll
    for (int i = 0; i < 2; ++i)
#pragma unroll
      for (int j = 0; j < 4; ++j) s[i][j] = z;
#pragma unroll
    for (int ks = 0; ks < 2; ++ks) {
      bf16x8_t kf[4];
      const int cb = ks * 64 + ((lane >> 4) << 4);
#pragma unroll
      for (int j = 0; j < 4; ++j) {
        const int row = j * 16 + (lane & 15);
        kf[j] = *(const bf16x8_t*)(k_lds + row * 128 + (cb ^ ((row & 7) << 4)));
      }
#pragma unroll
      for (int i = 0; i < 2; ++i)
#pragma unroll
        for (int j = 0; j < 4; ++j)
          s[i][j] = __builtin_amdgcn_mfma_f32_16x16x32_bf16(qf[i][ks], kf[j], s[i][j], 0, 0, 0);
    }

    // online softmax (wave-parallel: shfl over the 16-lane group holding each row)
#pragma unroll
    for (int i = 0; i < 2; ++i)
#pragma unroll
      for (int r = 0; r < 4; ++r) {
        float s0 = s[i][0][r] * (1.f/32.f);
        float s1 = s[i][1][r] * (1.f/32.f);
        float s2 = s[i][2][r] * (1.f/32.f);
        float s3 = s[i][3][r] * (1.f/32.f);
        float mx = fmaxf(fmaxf(s0, s1), fmaxf(s2, s3));
        mx = fmaxf(mx, __shfl_xor(mx, 1));
        mx = fmaxf(mx, __shfl_xor(mx, 2));
        mx = fmaxf(mx, __shfl_xor(mx, 4));
        mx = fmaxf(mx, __shfl_xor(mx, 8));
        const float mn = fmaxf(m_run[i][r], mx);
        const float fr = __expf(m_run[i][r] - mn);
        m_run[i][r] = mn;
        float p0 = __expf(s0 - mn), p1 = __expf(s1 - mn);
        float p2 = __expf(s2 - mn), p3 = __expf(s3 - mn);
        s[i][0][r] = p0; s[i][1][r] = p1; s[i][2][r] = p2; s[i][3][r] = p3;
        float sl = p0 + p1 + p2 + p3;
        sl += __shfl_xor(sl, 1);
        sl += __shfl_xor(sl, 2);
        sl += __shfl_xor(sl, 4);
        sl += __shfl_xor(sl, 8);
        l_run[i][r] = l_run[i][r] * fr + sl;
#pragma unroll
        for (int jd = 0; jd < 4; ++jd) o_acc[i][jd][r] *= fr;
      }

    // P -> per-wave LDS (C-layout scatter), then re-read as A-fragments
#pragma unroll
    for (int i = 0; i < 2; ++i)
#pragma unroll
      for (int j = 0; j < 4; ++j) {
        const int col = j * 16 + (lane & 15);
#pragma unroll
        for (int r = 0; r < 4; ++r) {
          const int row = i * 16 + ((lane >> 4) << 2) + r;
          *(unsigned short*)(p_lds + row * 144 + col * 2) = f2b(s[i][j][r]);
        }
      }

    // PV
#pragma unroll
    for (int ks = 0; ks < 2; ++ks) {
      const int cb = ks * 64 + ((lane >> 4) << 4);
      bf16x8_t pa[2], vf[4];
#pragma unroll
      for (int i = 0; i < 2; ++i)
        pa[i] = *(const bf16x8_t*)(p_lds + (i * 16 + (lane & 15)) * 144 + cb);
#pragma unroll
      for (int jd = 0; jd < 4; ++jd)
        vf[jd] = *(const bf16x8_t*)(vt_lds + (jd * 16 + (lane & 15)) * 144 + cb);
#pragma unroll
      for (int i = 0; i < 2; ++i)
#pragma unroll
        for (int jd = 0; jd < 4; ++jd)
          o_acc[i][jd] = __builtin_amdgcn_mfma_f32_16x16x32_bf16(pa[i], vf[jd], o_acc[i][jd], 0, 0, 0);
    }
  }

  // finalize: O = acc / l
#pragma unroll
  for (int i = 0; i < 2; ++i)
#pragma unroll
    for (int r = 0; r < 4; ++r) {
      const float inv = 1.f / l_run[i][r];
      const int qr = q0 + i * 16 + ((lane >> 4) << 2) + r;
#pragma unroll
      for (int jd = 0; jd < 4; ++jd) {
        const int cc = colb + jd * 16 + (lane & 15);
        O[(rowb + qr) * HDIM + cc] = f2b(o_acc[i][jd][r] * inv);
      }
    }
}

// ---------------- LayerNorm: fp32 in -> fp32 + bf16 out ----------------
__global__ __launch_bounds__(256) void ln_kernel(
    const float* __restrict__ y, const float* __restrict__ g, const float* __restrict__ be,
    float* __restrict__ xf, unsigned short* __restrict__ xb) {
  const int row = blockIdx.x;
  const int t = threadIdx.x;
  const float4 v = ((const float4*)(y + (size_t)row * HDIM))[t];
  float s  = v.x + v.y + v.z + v.w;
  float ss = v.x*v.x + v.y*v.y + v.z*v.z + v.w*v.w;
#pragma unroll
  for (int m = 1; m < 64; m <<= 1) { s += __shfl_xor(s, m); ss += __shfl_xor(ss, m); }
  __shared__ float rs[4], rss[4];
  const int w = t >> 6, lane = t & 63;
  if (lane == 0) { rs[w] = s; rss[w] = ss; }
  __syncthreads();
  s  = rs[0] + rs[1] + rs[2] + rs[3];
  ss = rss[0] + rss[1] + rss[2] + rss[3];
  const float mean = s * (1.f / HDIM);
  const float inv = rsqrtf(ss * (1.f / HDIM) - mean * mean + 1e-5f);
  const int c = t * 4;
  const float4 gg = *(const float4*)(g + c);
  const float4 bb = *(const float4*)(be + c);
  float4 o;
  o.x = (v.x - mean) * inv * gg.x + bb.x;
  o.y = (v.y - mean) * inv * gg.y + bb.y;
  o.z = (v.z - mean) * inv * gg.z + bb.z;
  o.w = (v.w - mean) * inv * gg.w + bb.w;
  ((float4*)(xf + (size_t)row * HDIM))[t] = o;
  ushort4 ob = { f2b(o.x), f2b(o.y), f2b(o.z), f2b(o.w) };
  ((ushort4*)(xb + (size_t)row * HDIM))[t] = ob;
}

// ---------------- host ----------------
extern "C" void kernel_launch(void* const* d_in, const int* in_sizes, int n_in,
                              void* d_out, int out_size, void* d_ws, size_t ws_size,
                              hipStream_t stream) {
  const float* input_x = (const float*)d_in[0];
  const float* emb_W   = (const float*)d_in[1];
  const float* emb_b   = (const float*)d_in[2];
  const float* pos_tab = (const float*)d_in[3];
  const float* Wq  = (const float*)d_in[4];
  const float* bq  = (const float*)d_in[5];
  const float* Wk  = (const float*)d_in[6];
  const float* bk  = (const float*)d_in[7];
  const float* Wv  = (const float*)d_in[8];
  const float* bv  = (const float*)d_in[9];
  const float* Wo  = (const float*)d_in[10];
  const float* bo  = (const float*)d_in[11];
  const float* ln1g = (const float*)d_in[12];
  const float* ln1b = (const float*)d_in[13];
  const float* W1  = (const float*)d_in[14];
  const float* b1  = (const float*)d_in[15];
  const float* W2  = (const float*)d_in[16];
  const float* b2  = (const float*)d_in[17];
  const float* ln2g = (const float*)d_in[18];
  const float* ln2b = (const float*)d_in[19];
  float* out = (float*)d_out;

  char* ws = (char*)d_ws;
  size_t off = 0;
  auto alloc = [&](size_t bytes) {
    char* p = ws + off;
    off += (bytes + 255) & ~(size_t)255;
    return p;
  };
  unsigned short* wqT = (unsigned short*)alloc((size_t)HDIM * HDIM * 2);
  unsigned short* wkT = (unsigned short*)alloc((size_t)HDIM * HDIM * 2);
  unsigned short* wvT = (unsigned short*)alloc((size_t)HDIM * HDIM * 2);
  unsigned short* woT = (unsigned short*)alloc((size_t)HDIM * HDIM * 2);
  unsigned short* w1T = (unsigned short*)alloc((size_t)PFF * HDIM * 2);   // [PF][H]
  unsigned short* w2T = (unsigned short*)alloc((size_t)HDIM * PFF * 2);   // [H][PF]
  unsigned short* embWT = (unsigned short*)alloc((size_t)HDIM * 256 * 2); // [H][IN]
  unsigned short* inb = (unsigned short*)alloc((size_t)MM * 256 * 2);
  unsigned short* xb  = (unsigned short*)alloc((size_t)MM * HDIM * 2);
  unsigned short* qb  = (unsigned short*)alloc((size_t)MM * HDIM * 2);
  unsigned short* kb  = (unsigned short*)alloc((size_t)MM * HDIM * 2);
  unsigned short* vb  = (unsigned short*)alloc((size_t)MM * HDIM * 2);
  (void)alloc((size_t)MM * PFF * 2 - 2 * (size_t)MM * HDIM * 2); // extra for hb span
  float* y = (float*)alloc((size_t)MM * HDIM * 4);
  unsigned short* ab = qb;   // attn out aliases qb (disjoint per-block r/w, safe)
  unsigned short* hb = kb;   // FFN hidden spans kb+vb+extra (kb/vb dead by FFN1)

  const dim3 blk256(256);
  const dim3 tblk(32, 8);

  // prep
  cvt_bf16<<<dim3(MM * 256 / 4 / 256), blk256, 0, stream>>>(input_x, inb, MM * 256 / 4);
  transpose_bf16<<<dim3(HDIM / 32, 256 / 32), tblk, 0, stream>>>(emb_W, embWT, 256, HDIM);

  // embedding: x = (input @ embW + b)*32 + pos   -> out(fp32) + xb(bf16)
  gemm_bt<true, false, false, true, true, true><<<dim3(HDIM / 128, MM / 128), blk256, 0, stream>>>(
      inb, embWT, emb_b, nullptr, pos_tab, out, xb, MM, HDIM, 256);

  for (int l = 0; l < NLAYER; ++l) {
    const size_t wofs = (size_t)l * HDIM * HDIM;
    transpose_bf16<<<dim3(32, 32), tblk, 0, stream>>>(Wq + wofs, wqT, HDIM, HDIM);
    transpose_bf16<<<dim3(32, 32), tblk, 0, stream>>>(Wk + wofs, wkT, HDIM, HDIM);
    transpose_bf16<<<dim3(32, 32), tblk, 0, stream>>>(Wv + wofs, wvT, HDIM, HDIM);
    transpose_bf16<<<dim3(32, 32), tblk, 0, stream>>>(Wo + wofs, woT, HDIM, HDIM);
    transpose_bf16<<<dim3(PFF / 32, HDIM / 32), tblk, 0, stream>>>(
        W1 + (size_t)l * HDIM * PFF, w1T, HDIM, PFF);
    transpose_bf16<<<dim3(HDIM / 32, PFF / 32), tblk, 0, stream>>>(
        W2 + (size_t)l * PFF * HDIM, w2T, PFF, HDIM);

    // QKV
    gemm_bt<true, false, false, false, false, true><<<dim3(8, 64), blk256, 0, stream>>>(
        xb, wqT, bq + l * HDIM, nullptr, nullptr, nullptr, qb, MM, HDIM, HDIM);
    gemm_bt<true, false, false, false, false, true><<<dim3(8, 64), blk256, 0, stream>>>(
        xb, wkT, bk + l * HDIM, nullptr, nullptr, nullptr, kb, MM, HDIM, HDIM);
    gemm_bt<true, false, false, false, false, true><<<dim3(8, 64), blk256, 0, stream>>>(
        xb, wvT, bv + l * HDIM, nullptr, nullptr, nullptr, vb, MM, HDIM, HDIM);

    attn_kernel<<<dim3(SS / 128, BB * NHEAD), blk256, 0, stream>>>(qb, kb, vb, ab);

    // O-proj + residual (resid = fp32 x in `out`)
    gemm_bt<true, false, true, false, true, false><<<dim3(8, 64), blk256, 0, stream>>>(
        ab, woT, bo + l * HDIM, out, nullptr, y, nullptr, MM, HDIM, HDIM);
    ln_kernel<<<dim3(MM), blk256, 0, stream>>>(y, ln1g + l * HDIM, ln1b + l * HDIM, out, xb);

    // FFN
    gemm_bt<true, true, false, false, false, true><<<dim3(PFF / 128, MM / 128), blk256, 0, stream>>>(
        xb, w1T, b1 + (size_t)l * PFF, nullptr, nullptr, nullptr, hb, MM, PFF, HDIM);
    gemm_bt<true, false, true, false, true, false><<<dim3(8, 64), blk256, 0, stream>>>(
        hb, w2T, b2 + l * HDIM, out, nullptr, y, nullptr, MM, HDIM, PFF);
    ln_kernel<<<dim3(MM), blk256, 0, stream>>>(y, ln2g + l * HDIM, ln2b + l * HDIM, out, xb);
  }
  (void)in_sizes; (void)n_in; (void)out_size; (void)ws_size;
}

// Round 2
// 2470.498 us; speedup vs baseline: 1.1447x; 1.1447x over previous
//
#include <hip/hip_runtime.h>

// ---------------- constants ----------------
#define HDIM 1024
#define BB 8
#define SS 1024
#define NHEAD 16
#define PFF 4096
#define NLAYER 6
#define MM (BB*SS)   // 8192 rows

typedef __attribute__((ext_vector_type(8))) short bf16x8_t;
typedef __attribute__((ext_vector_type(4))) float f32x4_t;
typedef __attribute__((ext_vector_type(16))) float f32x16_t;

static __device__ __forceinline__ unsigned short f2b(float f) {
  unsigned int u = __float_as_uint(f);
  u += 0x7fffu + ((u >> 16) & 1u);      // RNE
  return (unsigned short)(u >> 16);
}

static __device__ __forceinline__ unsigned pkbf(float lo, float hi) {
  unsigned r;
  asm("v_cvt_pk_bf16_f32 %0, %1, %2" : "=v"(r) : "v"(lo), "v"(hi));
  return r;
}

static __device__ __forceinline__ bf16x8_t mk8(unsigned a, unsigned b, unsigned c, unsigned d) {
  union { unsigned u[4]; bf16x8_t v; } x;
  x.u[0] = a; x.u[1] = b; x.u[2] = c; x.u[3] = d;
  return x.v;
}

static __device__ __forceinline__ void gload16(const void* g, void* l) {
  __builtin_amdgcn_global_load_lds((__attribute__((address_space(1))) void*)g,
                                   (__attribute__((address_space(3))) void*)l, 16, 0, 0);
}

// ---------------- fp32 -> bf16 convert ----------------
__global__ __launch_bounds__(256) void cvt_bf16(const float* __restrict__ in,
                                                unsigned short* __restrict__ o, int n4) {
  const int i = blockIdx.x * 256 + threadIdx.x;
  if (i < n4) {
    const float4 v = ((const float4*)in)[i];
    ushort4 ob = { f2b(v.x), f2b(v.y), f2b(v.z), f2b(v.w) };
    ((ushort4*)o)[i] = ob;
  }
}

// ---------------- transpose fp32 [R][C] -> bf16 [C][R] ----------------
__global__ __launch_bounds__(256) void transpose_bf16(const float* __restrict__ in,
                                                      unsigned short* __restrict__ outT,
                                                      int R, int C) {
  __shared__ float tile[32][33];
  const int c0 = blockIdx.x * 32, r0 = blockIdx.y * 32;
  const int tx = threadIdx.x, ty = threadIdx.y;   // (32,8)
#pragma unroll
  for (int i = 0; i < 4; ++i)
    tile[ty + 8*i][tx] = in[(size_t)(r0 + ty + 8*i) * C + c0 + tx];
  __syncthreads();
#pragma unroll
  for (int i = 0; i < 4; ++i)
    outT[(size_t)(c0 + ty + 8*i) * R + r0 + tx] = f2b(tile[tx][ty + 8*i]);
}

// ---------------- V^T extraction: qkv[M][3072] (V at col 2048+) -> vt[bh][64][1024] ----------------
__global__ __launch_bounds__(256) void vtrans(const unsigned short* __restrict__ qkv,
                                              unsigned short* __restrict__ vt) {
  __shared__ unsigned short tile[32][34];
  const int s0 = blockIdx.x * 32;
  const int by = blockIdx.y;           // bh*2 + dt
  const int bh = by >> 1, dt = by & 1;
  const int b = bh >> 4, h = bh & 15;
  const int tx = threadIdx.x, ty = threadIdx.y;  // (32,8)
  const unsigned short* src = qkv + ((size_t)(b * 1024 + s0)) * 3072 + 2048 + h * 64 + dt * 32;
#pragma unroll
  for (int i = 0; i < 4; ++i)
    tile[ty + 8*i][tx] = src[(size_t)(ty + 8*i) * 3072 + tx];
  __syncthreads();
  unsigned short* dst = vt + (size_t)(bh * 64 + dt * 32) * 1024 + s0;
#pragma unroll
  for (int i = 0; i < 4; ++i)
    dst[(size_t)(ty + 8*i) * 1024 + tx] = tile[tx][ty + 8*i];
}

// ---------------- bias concat for fused QKV ----------------
__global__ __launch_bounds__(256) void concat_bias(const float* __restrict__ bq,
                                                   const float* __restrict__ bk,
                                                   const float* __restrict__ bv,
                                                   float* __restrict__ o) {
  const int i = blockIdx.x * 256 + threadIdx.x;   // 0..3071
  o[i] = (i < 1024) ? bq[i] : ((i < 2048) ? bk[i - 1024] : bv[i - 2048]);
}

// ---------------- GEMM: A[M][K] bf16 @ Bt[N][K] bf16 -> out[M][N] ----------------
template<bool BIAS, bool RELU, bool RESID, bool EMB, bool WF32, bool WBF16>
__global__ __launch_bounds__(256) void gemm_bt(
    const unsigned short* __restrict__ A,
    const unsigned short* __restrict__ Bt,
    const float* __restrict__ bias,
    const float* __restrict__ resid,
    const float* __restrict__ pos,
    float* __restrict__ outf,
    unsigned short* __restrict__ outb,
    int M, int N, int K) {
  __shared__ __align__(1024) char smem[32768];   // A 16KB | B 16KB
  const int t = threadIdx.x;
  const int lane = t & 63;
  const int w = t >> 6;
  const int wr = w >> 1, wc = w & 1;
  const int m0 = blockIdx.y * 128;
  const int n0 = blockIdx.x * 128;

  const f32x4_t z = {0.f, 0.f, 0.f, 0.f};
  f32x4_t acc[4][4];
#pragma unroll
  for (int i = 0; i < 4; ++i)
#pragma unroll
    for (int j = 0; j < 4; ++j) acc[i][j] = z;

  const int nkt = K >> 6;
  for (int kt = 0; kt < nkt; ++kt) {
#pragma unroll
    for (int i = 0; i < 4; ++i) {
      const int chunk = i * 4 + w;                 // wave-uniform 1KB chunk
      const int byteoff = chunk * 1024 + lane * 16;
      const int row = byteoff >> 7;                // tile row (0..127)
      const int scb = (byteoff & 127) ^ ((row & 7) << 4);
      gload16((const char*)A  + ((size_t)(m0 + row) * K + (kt << 6)) * 2 + scb,
              smem + chunk * 1024);
      gload16((const char*)Bt + ((size_t)(n0 + row) * K + (kt << 6)) * 2 + scb,
              smem + 16384 + chunk * 1024);
    }
    __syncthreads();
#pragma unroll
    for (int ks = 0; ks < 2; ++ks) {
      bf16x8_t af[4], bfv[4];
      const int cb = ks * 64 + ((lane >> 4) << 4);
#pragma unroll
      for (int i = 0; i < 4; ++i) {
        const int ra = wr * 64 + i * 16 + (lane & 15);
        af[i]  = *(const bf16x8_t*)(smem + ra * 128 + (cb ^ ((ra & 7) << 4)));
        const int rb = wc * 64 + i * 16 + (lane & 15);
        bfv[i] = *(const bf16x8_t*)(smem + 16384 + rb * 128 + (cb ^ ((rb & 7) << 4)));
      }
#pragma unroll
      for (int i = 0; i < 4; ++i)
#pragma unroll
        for (int j = 0; j < 4; ++j)
          acc[i][j] = __builtin_amdgcn_mfma_f32_16x16x32_bf16(af[i], bfv[j], acc[i][j], 0, 0, 0);
    }
    __syncthreads();
  }

  // epilogue: C/D layout col=lane&15, row=(lane>>4)*4+r
#pragma unroll
  for (int i = 0; i < 4; ++i) {
    const int rbase = m0 + wr * 64 + i * 16 + ((lane >> 4) << 2);
#pragma unroll
    for (int j = 0; j < 4; ++j) {
      const int cc = n0 + wc * 64 + j * 16 + (lane & 15);
      float bv = 0.f;
      if (BIAS) bv = bias[cc];
#pragma unroll
      for (int r = 0; r < 4; ++r) {
        const int row = rbase + r;
        float v = acc[i][j][r] + bv;
        if (EMB)  v = v * 32.f + pos[(size_t)(row & (SS - 1)) * N + cc];
        if (RELU) v = fmaxf(v, 0.f);
        if (RESID) v += resid[(size_t)row * N + cc];
        if (WF32)  outf[(size_t)row * N + cc] = v;
        if (WBF16) outb[(size_t)row * N + cc] = f2b(v);
      }
    }
  }
}

// ---------------- flash attention, swapped-QK^T in-register softmax ----------------
// grid (S/128, B*NH), 256 threads (4 waves x 32 q-rows). KV tiles of 64.
// QK^T: mfma(K, Q) 32x32x16 -> P^T (col = q = lane&31). Softmax per-lane.
// PV:   mfma(V^T, P) -> o^T (col = q) so rescale factor is lane-uniform.
__global__ __launch_bounds__(256) void attn2(
    const unsigned short* __restrict__ qkv,   // [M][3072]: Q|K|V
    const unsigned short* __restrict__ vt,    // [bh][64][1024] = V^T per head
    unsigned short* __restrict__ O) {         // [M][1024]
  __shared__ __align__(1024) char smem[2 * 16384];   // dbuf x (K 8KB | VT 8KB)
  const int t = threadIdx.x, lane = t & 63, w = t >> 6;
  const int l31 = lane & 31, lg = lane >> 5;   // lane group (0/1)
  const int bh = blockIdx.y;
  const int b = bh >> 4, h = bh & 15;
  const size_t rowb = (size_t)b << 10;
  const int q0 = blockIdx.x * 128 + w * 32;

  // Q fragments (B-operand rows=q along d): lane: q=l31, d = dd*16 + lg*8 + j
  bf16x8_t qf[4];
  {
    const unsigned short* Qp = qkv + (rowb + q0 + l31) * 3072 + h * 64 + lg * 8;
#pragma unroll
    for (int dd = 0; dd < 4; ++dd) qf[dd] = *(const bf16x8_t*)(Qp + dd * 16);
  }

  f32x16_t oa0, oa1;
#pragma unroll
  for (int r = 0; r < 16; ++r) { oa0[r] = 0.f; oa1[r] = 0.f; }
  float m_run = -1e30f, l_run = 0.f;
  const float inv32 = 1.f / 32.f;

  const char* kglob = (const char*)qkv + ((size_t)1024 + h * 64) * 2;   // K col base (bytes added per row)
  const char* vglob = (const char*)vt + (size_t)bh * 64 * 1024 * 2;

  // stage tile kt into buffer buf (4 waves x 2 chunks each for K and VT)
  auto stage = [&](int kt, int buf) {
    char* kbuf = smem + buf * 16384;
    char* vbuf = kbuf + 8192;
#pragma unroll
    for (int i = 0; i < 2; ++i) {
      const int chunk = w * 2 + i;                 // 0..7
      const int byteoff = chunk * 1024 + lane * 16;
      const int row = byteoff >> 7;                // 0..63
      const int scb = (byteoff & 127) ^ ((row & 7) << 4);
      gload16(kglob + (size_t)(rowb + kt * 64 + row) * 6144 + scb, kbuf + chunk * 1024);
      gload16(vglob + ((size_t)row * 1024 + kt * 64) * 2 + scb,    vbuf + chunk * 1024);
    }
  };

  stage(0, 0);
  for (int kt = 0; kt < 16; ++kt) {
    const int cb = kt & 1;
    __syncthreads();                       // staged loads for buf cb drained + visible
    if (kt < 15) stage(kt + 1, cb ^ 1);    // async prefetch overlaps compute
    const char* kbuf = smem + cb * 16384;
    const char* vbuf = kbuf + 8192;

    // ---- QK^T (swapped): p = K x Q^T -> P^T fragment (rows k, cols q) ----
    f32x16_t p0, p1;
#pragma unroll
    for (int r = 0; r < 16; ++r) { p0[r] = 0.f; p1[r] = 0.f; }
    __builtin_amdgcn_s_setprio(1);
#pragma unroll
    for (int dd = 0; dd < 4; ++dd) {
      {
        const int row = l31;
        const int col = (dd * 32 + (lg << 4)) ^ ((row & 7) << 4);
        bf16x8_t kf = *(const bf16x8_t*)(kbuf + row * 128 + col);
        p0 = __builtin_amdgcn_mfma_f32_32x32x16_bf16(kf, qf[dd], p0, 0, 0, 0);
      }
      {
        const int row = 32 + l31;
        const int col = (dd * 32 + (lg << 4)) ^ ((row & 7) << 4);
        bf16x8_t kf = *(const bf16x8_t*)(kbuf + row * 128 + col);
        p1 = __builtin_amdgcn_mfma_f32_32x32x16_bf16(kf, qf[dd], p1, 0, 0, 0);
      }
    }
    __builtin_amdgcn_s_setprio(0);

    // ---- online softmax, fully in-register (lane owns q = l31) ----
    float mx = p0[0];
#pragma unroll
    for (int r = 1; r < 16; ++r) mx = fmaxf(mx, p0[r]);
#pragma unroll
    for (int r = 0; r < 16; ++r) mx = fmaxf(mx, p1[r]);
    mx = fmaxf(mx, __shfl_xor(mx, 32));
    const float mn = fmaxf(m_run, mx * inv32);
    const float fr = __expf(m_run - mn);
    m_run = mn;
    float sum = 0.f;
#pragma unroll
    for (int r = 0; r < 16; ++r) { const float e = __expf(p0[r] * inv32 - mn); p0[r] = e; sum += e; }
#pragma unroll
    for (int r = 0; r < 16; ++r) { const float e = __expf(p1[r] * inv32 - mn); p1[r] = e; sum += e; }
    sum += __shfl_xor(sum, 32);
    l_run = l_run * fr + sum;
#pragma unroll
    for (int r = 0; r < 16; ++r) { oa0[r] *= fr; oa1[r] *= fr; }

    // ---- build P fragments (rows q along k) via cvt_pk + shfl_xor(32) ----
    const unsigned A0 = pkbf(p0[0], p0[1]),  B0 = pkbf(p0[2], p0[3]);
    const unsigned C0 = pkbf(p0[4], p0[5]),  D0 = pkbf(p0[6], p0[7]);
    const unsigned E0 = pkbf(p0[8], p0[9]),  F0 = pkbf(p0[10], p0[11]);
    const unsigned G0 = pkbf(p0[12], p0[13]), H0 = pkbf(p0[14], p0[15]);
    const unsigned A1 = pkbf(p1[0], p1[1]),  B1 = pkbf(p1[2], p1[3]);
    const unsigned C1 = pkbf(p1[4], p1[5]),  D1 = pkbf(p1[6], p1[7]);
    const unsigned E1 = pkbf(p1[8], p1[9]),  F1 = pkbf(p1[10], p1[11]);
    const unsigned G1 = pkbf(p1[12], p1[13]), H1 = pkbf(p1[14], p1[15]);
    const unsigned sA0 = __shfl_xor((int)A0, 32), sB0 = __shfl_xor((int)B0, 32);
    const unsigned sC0 = __shfl_xor((int)C0, 32), sD0 = __shfl_xor((int)D0, 32);
    const unsigned sE0 = __shfl_xor((int)E0, 32), sF0 = __shfl_xor((int)F0, 32);
    const unsigned sG0 = __shfl_xor((int)G0, 32), sH0 = __shfl_xor((int)H0, 32);
    const unsigned sA1 = __shfl_xor((int)A1, 32), sB1 = __shfl_xor((int)B1, 32);
    const unsigned sC1 = __shfl_xor((int)C1, 32), sD1 = __shfl_xor((int)D1, 32);
    const unsigned sE1 = __shfl_xor((int)E1, 32), sF1 = __shfl_xor((int)F1, 32);
    const unsigned sG1 = __shfl_xor((int)G1, 32), sH1 = __shfl_xor((int)H1, 32);
    const bool hi = (lg != 0);
    bf16x8_t pf[4];
    pf[0] = hi ? mk8(sC0, sD0, C0, D0) : mk8(A0, B0, sA0, sB0);
    pf[1] = hi ? mk8(sG0, sH0, G0, H0) : mk8(E0, F0, sE0, sF0);
    pf[2] = hi ? mk8(sC1, sD1, C1, D1) : mk8(A1, B1, sA1, sB1);
    pf[3] = hi ? mk8(sG1, sH1, G1, H1) : mk8(E1, F1, sE1, sF1);

    // ---- PV: o^T += V^T x P (rows d, cols q) ----
    __builtin_amdgcn_s_setprio(1);
#pragma unroll
    for (int c = 0; c < 4; ++c) {
      {
        const int row = l31;
        const int col = (c * 32 + (lg << 4)) ^ ((row & 7) << 4);
        bf16x8_t vf = *(const bf16x8_t*)(vbuf + row * 128 + col);
        oa0 = __builtin_amdgcn_mfma_f32_32x32x16_bf16(vf, pf[c], oa0, 0, 0, 0);
      }
      {
        const int row = 32 + l31;
        const int col = (c * 32 + (lg << 4)) ^ ((row & 7) << 4);
        bf16x8_t vf = *(const bf16x8_t*)(vbuf + row * 128 + col);
        oa1 = __builtin_amdgcn_mfma_f32_32x32x16_bf16(vf, pf[c], oa1, 0, 0, 0);
      }
    }
    __builtin_amdgcn_s_setprio(0);
  }

  // ---- epilogue: O[q][d] = o^T / l ----
  const float inv = 1.f / l_run;
  unsigned short* op = O + (rowb + q0 + l31) * 1024 + h * 64 + (lg << 2);
#pragma unroll
  for (int rg = 0; rg < 4; ++rg) {
    const unsigned u0 = pkbf(oa0[rg * 4 + 0] * inv, oa0[rg * 4 + 1] * inv);
    const unsigned u1 = pkbf(oa0[rg * 4 + 2] * inv, oa0[rg * 4 + 3] * inv);
    uint2 st = { u0, u1 };
    *(uint2*)(op + rg * 8) = st;
    const unsigned v0 = pkbf(oa1[rg * 4 + 0] * inv, oa1[rg * 4 + 1] * inv);
    const unsigned v1 = pkbf(oa1[rg * 4 + 2] * inv, oa1[rg * 4 + 3] * inv);
    uint2 st2 = { v0, v1 };
    *(uint2*)(op + 32 + rg * 8) = st2;
  }
}

// ---------------- LayerNorm: fp32 in -> fp32 + bf16 out ----------------
__global__ __launch_bounds__(256) void ln_kernel(
    const float* __restrict__ y, const float* __restrict__ g, const float* __restrict__ be,
    float* __restrict__ xf, unsigned short* __restrict__ xb) {
  const int row = blockIdx.x;
  const int t = threadIdx.x;
  const float4 v = ((const float4*)(y + (size_t)row * HDIM))[t];
  float s  = v.x + v.y + v.z + v.w;
  float ss = v.x*v.x + v.y*v.y + v.z*v.z + v.w*v.w;
#pragma unroll
  for (int m = 1; m < 64; m <<= 1) { s += __shfl_xor(s, m); ss += __shfl_xor(ss, m); }
  __shared__ float rs[4], rss[4];
  const int w = t >> 6, lane = t & 63;
  if (lane == 0) { rs[w] = s; rss[w] = ss; }
  __syncthreads();
  s  = rs[0] + rs[1] + rs[2] + rs[3];
  ss = rss[0] + rss[1] + rss[2] + rss[3];
  const float mean = s * (1.f / HDIM);
  const float inv = rsqrtf(ss * (1.f / HDIM) - mean * mean + 1e-5f);
  const int c = t * 4;
  const float4 gg = *(const float4*)(g + c);
  const float4 bb = *(const float4*)(be + c);
  float4 o;
  o.x = (v.x - mean) * inv * gg.x + bb.x;
  o.y = (v.y - mean) * inv * gg.y + bb.y;
  o.z = (v.z - mean) * inv * gg.z + bb.z;
  o.w = (v.w - mean) * inv * gg.w + bb.w;
  ((float4*)(xf + (size_t)row * HDIM))[t] = o;
  ushort4 ob = { f2b(o.x), f2b(o.y), f2b(o.z), f2b(o.w) };
  ((ushort4*)(xb + (size_t)row * HDIM))[t] = ob;
}

// ---------------- host ----------------
extern "C" void kernel_launch(void* const* d_in, const int* in_sizes, int n_in,
                              void* d_out, int out_size, void* d_ws, size_t ws_size,
                              hipStream_t stream) {
  const float* input_x = (const float*)d_in[0];
  const float* emb_W   = (const float*)d_in[1];
  const float* emb_b   = (const float*)d_in[2];
  const float* pos_tab = (const float*)d_in[3];
  const float* Wq  = (const float*)d_in[4];
  const float* bq  = (const float*)d_in[5];
  const float* Wk  = (const float*)d_in[6];
  const float* bk  = (const float*)d_in[7];
  const float* Wv  = (const float*)d_in[8];
  const float* bv  = (const float*)d_in[9];
  const float* Wo  = (const float*)d_in[10];
  const float* bo  = (const float*)d_in[11];
  const float* ln1g = (const float*)d_in[12];
  const float* ln1b = (const float*)d_in[13];
  const float* W1  = (const float*)d_in[14];
  const float* b1  = (const float*)d_in[15];
  const float* W2  = (const float*)d_in[16];
  const float* b2  = (const float*)d_in[17];
  const float* ln2g = (const float*)d_in[18];
  const float* ln2b = (const float*)d_in[19];
  float* out = (float*)d_out;

  char* ws = (char*)d_ws;
  size_t off = 0;
  auto alloc = [&](size_t bytes) {
    char* p = ws + off;
    off += (bytes + 255) & ~(size_t)255;
    return p;
  };
  unsigned short* wqkvT = (unsigned short*)alloc((size_t)3072 * HDIM * 2);
  unsigned short* woT   = (unsigned short*)alloc((size_t)HDIM * HDIM * 2);
  unsigned short* w1T   = (unsigned short*)alloc((size_t)PFF * HDIM * 2);   // [PF][H]
  unsigned short* w2T   = (unsigned short*)alloc((size_t)HDIM * PFF * 2);   // [H][PF]
  unsigned short* embWT = (unsigned short*)alloc((size_t)HDIM * 256 * 2);   // [H][IN]
  float*          bqkv  = (float*)alloc(3072 * 4);
  unsigned short* inb   = (unsigned short*)alloc((size_t)MM * 256 * 2);
  unsigned short* xb    = (unsigned short*)alloc((size_t)MM * HDIM * 2);
  unsigned short* qkvb  = (unsigned short*)alloc((size_t)MM * 3072 * 2);    // 48MB
  unsigned short* vtb   = (unsigned short*)alloc((size_t)MM * HDIM * 2);    // 16MB
  unsigned short* ab    = (unsigned short*)alloc((size_t)MM * HDIM * 2);
  float* y = (float*)alloc((size_t)MM * HDIM * 4);
  unsigned short* hb = qkvb;   // FFN hidden [M][4096] spans qkvb+vtb (dead by FFN1)

  const dim3 blk256(256);
  const dim3 tblk(32, 8);

  // prep
  cvt_bf16<<<dim3(MM * 256 / 4 / 256), blk256, 0, stream>>>(input_x, inb, MM * 256 / 4);
  transpose_bf16<<<dim3(HDIM / 32, 256 / 32), tblk, 0, stream>>>(emb_W, embWT, 256, HDIM);

  // embedding: x = (input @ embW + b)*32 + pos   -> out(fp32) + xb(bf16)
  gemm_bt<true, false, false, true, true, true><<<dim3(HDIM / 128, MM / 128), blk256, 0, stream>>>(
      inb, embWT, emb_b, nullptr, pos_tab, out, xb, MM, HDIM, 256);

  for (int l = 0; l < NLAYER; ++l) {
    const size_t wofs = (size_t)l * HDIM * HDIM;
    transpose_bf16<<<dim3(32, 32), tblk, 0, stream>>>(Wq + wofs, wqkvT,                 HDIM, HDIM);
    transpose_bf16<<<dim3(32, 32), tblk, 0, stream>>>(Wk + wofs, wqkvT + 1024 * 1024,   HDIM, HDIM);
    transpose_bf16<<<dim3(32, 32), tblk, 0, stream>>>(Wv + wofs, wqkvT + 2048 * 1024,   HDIM, HDIM);
    transpose_bf16<<<dim3(32, 32), tblk, 0, stream>>>(Wo + wofs, woT, HDIM, HDIM);
    transpose_bf16<<<dim3(PFF / 32, HDIM / 32), tblk, 0, stream>>>(
        W1 + (size_t)l * HDIM * PFF, w1T, HDIM, PFF);
    transpose_bf16<<<dim3(HDIM / 32, PFF / 32), tblk, 0, stream>>>(
        W2 + (size_t)l * PFF * HDIM, w2T, PFF, HDIM);
    concat_bias<<<dim3(12), blk256, 0, stream>>>(bq + l * HDIM, bk + l * HDIM, bv + l * HDIM, bqkv);

    // fused QKV GEMM -> qkvb [M][3072]
    gemm_bt<true, false, false, false, false, true><<<dim3(24, 64), blk256, 0, stream>>>(
        xb, wqkvT, bqkv, nullptr, nullptr, nullptr, qkvb, MM, 3072, HDIM);

    // V^T per head
    vtrans<<<dim3(32, 256), tblk, 0, stream>>>(qkvb, vtb);

    // attention
    attn2<<<dim3(SS / 128, BB * NHEAD), blk256, 0, stream>>>(qkvb, vtb, ab);

    // O-proj + residual (resid = fp32 x in `out`)
    gemm_bt<true, false, true, false, true, false><<<dim3(8, 64), blk256, 0, stream>>>(
        ab, woT, bo + l * HDIM, out, nullptr, y, nullptr, MM, HDIM, HDIM);
    ln_kernel<<<dim3(MM), blk256, 0, stream>>>(y, ln1g + l * HDIM, ln1b + l * HDIM, out, xb);

    // FFN
    gemm_bt<true, true, false, false, false, true><<<dim3(PFF / 128, MM / 128), blk256, 0, stream>>>(
        xb, w1T, b1 + (size_t)l * PFF, nullptr, nullptr, nullptr, hb, MM, PFF, HDIM);
    gemm_bt<true, false, true, false, true, false><<<dim3(8, 64), blk256, 0, stream>>>(
        hb, w2T, b2 + l * HDIM, out, nullptr, y, nullptr, MM, HDIM, PFF);
    ln_kernel<<<dim3(MM), blk256, 0, stream>>>(y, ln2g + l * HDIM, ln2b + l * HDIM, out, xb);
  }
  (void)in_sizes; (void)n_in; (void)out_size; (void)ws_size;
}

// Round 3
// 2279.759 us; speedup vs baseline: 1.2405x; 1.0837x over previous
//
#include <hip/hip_runtime.h>

// ---------------- constants ----------------
#define HDIM 1024
#define BB 8
#define SS 1024
#define NHEAD 16
#define PFF 4096
#define NLAYER 6
#define MM (BB*SS)   // 8192 rows

typedef __attribute__((ext_vector_type(8))) short bf16x8_t;
typedef __attribute__((ext_vector_type(4))) float f32x4_t;
typedef __attribute__((ext_vector_type(16))) float f32x16_t;

static __device__ __forceinline__ unsigned short f2b(float f) {
  unsigned int u = __float_as_uint(f);
  u += 0x7fffu + ((u >> 16) & 1u);      // RNE
  return (unsigned short)(u >> 16);
}

static __device__ __forceinline__ unsigned pkbf(float lo, float hi) {
  unsigned r;
  asm("v_cvt_pk_bf16_f32 %0, %1, %2" : "=v"(r) : "v"(lo), "v"(hi));
  return r;
}

static __device__ __forceinline__ bf16x8_t mk8(unsigned a, unsigned b, unsigned c, unsigned d) {
  union { unsigned u[4]; bf16x8_t v; } x;
  x.u[0] = a; x.u[1] = b; x.u[2] = c; x.u[3] = d;
  return x.v;
}

static __device__ __forceinline__ void gload16(const void* g, void* l) {
  __builtin_amdgcn_global_load_lds((__attribute__((address_space(1))) void*)g,
                                   (__attribute__((address_space(3))) void*)l, 16, 0, 0);
}

template<int N>
static __device__ __forceinline__ void vwait() {
  asm volatile("s_waitcnt vmcnt(%0)" :: "n"(N) : "memory");
}

static __device__ __forceinline__ void bar() {
  asm volatile("" ::: "memory");
  __builtin_amdgcn_s_barrier();
  asm volatile("" ::: "memory");
}

// ---------------- fp32 -> bf16 convert ----------------
__global__ __launch_bounds__(256) void cvt_bf16(const float* __restrict__ in,
                                                unsigned short* __restrict__ o, int n4) {
  const int i = blockIdx.x * 256 + threadIdx.x;
  if (i < n4) {
    const float4 v = ((const float4*)in)[i];
    ushort4 ob = { f2b(v.x), f2b(v.y), f2b(v.z), f2b(v.w) };
    ((ushort4*)o)[i] = ob;
  }
}

// ---------------- transpose fp32 [R][C] -> bf16 [C][R] ----------------
__global__ __launch_bounds__(256) void transpose_bf16(const float* __restrict__ in,
                                                      unsigned short* __restrict__ outT,
                                                      int R, int C) {
  __shared__ float tile[32][33];
  const int c0 = blockIdx.x * 32, r0 = blockIdx.y * 32;
  const int tx = threadIdx.x, ty = threadIdx.y;   // (32,8)
#pragma unroll
  for (int i = 0; i < 4; ++i)
    tile[ty + 8*i][tx] = in[(size_t)(r0 + ty + 8*i) * C + c0 + tx];
  __syncthreads();
#pragma unroll
  for (int i = 0; i < 4; ++i)
    outT[(size_t)(c0 + ty + 8*i) * R + r0 + tx] = f2b(tile[tx][ty + 8*i]);
}

// ---------------- V^T extraction: qkv[M][3072] (V at col 2048+) -> vt[bh][64][1024] ----------------
__global__ __launch_bounds__(256) void vtrans(const unsigned short* __restrict__ qkv,
                                              unsigned short* __restrict__ vt) {
  __shared__ unsigned short tile[32][34];
  const int s0 = blockIdx.x * 32;
  const int by = blockIdx.y;           // bh*2 + dt
  const int bh = by >> 1, dt = by & 1;
  const int b = bh >> 4, h = bh & 15;
  const int tx = threadIdx.x, ty = threadIdx.y;  // (32,8)
  const unsigned short* src = qkv + ((size_t)(b * 1024 + s0)) * 3072 + 2048 + h * 64 + dt * 32;
#pragma unroll
  for (int i = 0; i < 4; ++i)
    tile[ty + 8*i][tx] = src[(size_t)(ty + 8*i) * 3072 + tx];
  __syncthreads();
  unsigned short* dst = vt + (size_t)(bh * 64 + dt * 32) * 1024 + s0;
#pragma unroll
  for (int i = 0; i < 4; ++i)
    dst[(size_t)(ty + 8*i) * 1024 + tx] = tile[tx][ty + 8*i];
}

// ---------------- bias concat for fused QKV ----------------
__global__ __launch_bounds__(256) void concat_bias(const float* __restrict__ bq,
                                                   const float* __restrict__ bk,
                                                   const float* __restrict__ bv,
                                                   float* __restrict__ o) {
  const int i = blockIdx.x * 256 + threadIdx.x;   // 0..3071
  o[i] = (i < 1024) ? bq[i] : ((i < 2048) ? bk[i - 1024] : bv[i - 2048]);
}

// ---------------- GEMM 256xBN, 8 waves, dbuf LDS, counted vmcnt ----------------
// A[M][K] bf16 @ Bt[N][K] bf16 -> out[M][N]. BK=64. 512 threads (2x4 waves),
// per-wave output 128 x (BN/4). Raw s_barrier + counted vmcnt: prefetch tile
// t+2 issued at end of iter t, waits never drain to 0 in steady state.
template<int BN, bool BIAS, bool RELU, bool RESID, bool EMB, bool WF32, bool WBF16>
__global__ __launch_bounds__(512, 2) void gemm256(
    const unsigned short* __restrict__ A,
    const unsigned short* __restrict__ Bt,
    const float* __restrict__ bias,
    const float* __restrict__ resid,
    const float* __restrict__ pos,
    float* __restrict__ outf,
    unsigned short* __restrict__ outb,
    int M, int N, int K) {
  constexpr int BUFSZ = 32768 + BN * 128;        // A 32KB + B tile
  constexpr int NJ = BN / 64;                    // B frags per wave (4 or 2)
  constexpr int WCN = BN / 4;                    // per-wave col span
  constexpr int BI = BN / 64;                    // B stage iters per wave
  constexpr int LPT = 4 + BI;                    // loads per thread per K-tile
  __shared__ __align__(1024) char smem[2 * BUFSZ];
  const int t = threadIdx.x, lane = t & 63, w = t >> 6;
  const int wr = w >> 2, wc = w & 3;

  // bijective XCD swizzle (all grids here are divisible by 8)
  int flat = blockIdx.x + gridDim.x * blockIdx.y;
  const int cpx = (gridDim.x * gridDim.y) >> 3;
  flat = (flat & 7) * cpx + (flat >> 3);
  const int m0 = (flat / gridDim.x) * 256;
  const int n0 = (flat % gridDim.x) * BN;

  const f32x4_t z = {0.f, 0.f, 0.f, 0.f};
  f32x4_t acc[8][NJ];
#pragma unroll
  for (int i = 0; i < 8; ++i)
#pragma unroll
    for (int j = 0; j < NJ; ++j) acc[i][j] = z;

  auto stage = [&](int kt, int buf) {
    char* ab_ = smem + buf * BUFSZ;
    char* bb_ = ab_ + 32768;
#pragma unroll
    for (int i = 0; i < 4; ++i) {
      const int chunk = i * 8 + w;
      const int byteoff = chunk * 1024 + lane * 16;
      const int row = byteoff >> 7;
      const int scb = (byteoff & 127) ^ ((row & 7) << 4);
      gload16((const char*)A + ((size_t)(m0 + row) * K + (kt << 6)) * 2 + scb,
              ab_ + chunk * 1024);
    }
#pragma unroll
    for (int i = 0; i < BI; ++i) {
      const int chunk = i * 8 + w;
      const int byteoff = chunk * 1024 + lane * 16;
      const int row = byteoff >> 7;
      const int scb = (byteoff & 127) ^ ((row & 7) << 4);
      gload16((const char*)Bt + ((size_t)(n0 + row) * K + (kt << 6)) * 2 + scb,
              bb_ + chunk * 1024);
    }
  };

  const int nkt = K >> 6;
  // prologue: tiles 0 and 1 in flight
  stage(0, 0);
  stage(1, 1);
  vwait<LPT>();          // tile 0 (own loads) landed
  bar();                 // everyone's tile-0 loads landed

  int cur = 0;
  for (int kt = 0; kt < nkt; ++kt) {
    const char* ab_ = smem + cur * BUFSZ;
    const char* bb_ = ab_ + 32768;

    bf16x8_t bfr[NJ][2], afr[4][2];
#pragma unroll
    for (int j = 0; j < NJ; ++j)
#pragma unroll
      for (int ks = 0; ks < 2; ++ks) {
        const int row = wc * WCN + j * 16 + (lane & 15);
        const int cb = ks * 64 + ((lane >> 4) << 4);
        bfr[j][ks] = *(const bf16x8_t*)(bb_ + row * 128 + (cb ^ ((row & 7) << 4)));
      }
#pragma unroll
    for (int i = 0; i < 4; ++i)
#pragma unroll
      for (int ks = 0; ks < 2; ++ks) {
        const int row = wr * 128 + i * 16 + (lane & 15);
        const int cb = ks * 64 + ((lane >> 4) << 4);
        afr[i][ks] = *(const bf16x8_t*)(ab_ + row * 128 + (cb ^ ((row & 7) << 4)));
      }
    __builtin_amdgcn_s_setprio(1);
#pragma unroll
    for (int ks = 0; ks < 2; ++ks)
#pragma unroll
      for (int i = 0; i < 4; ++i)
#pragma unroll
        for (int j = 0; j < NJ; ++j)
          acc[i][j] = __builtin_amdgcn_mfma_f32_16x16x32_bf16(afr[i][ks], bfr[j][ks], acc[i][j], 0, 0, 0);
    __builtin_amdgcn_s_setprio(0);
#pragma unroll
    for (int i = 0; i < 4; ++i)
#pragma unroll
      for (int ks = 0; ks < 2; ++ks) {
        const int row = wr * 128 + 64 + i * 16 + (lane & 15);
        const int cb = ks * 64 + ((lane >> 4) << 4);
        afr[i][ks] = *(const bf16x8_t*)(ab_ + row * 128 + (cb ^ ((row & 7) << 4)));
      }
    __builtin_amdgcn_s_setprio(1);
#pragma unroll
    for (int ks = 0; ks < 2; ++ks)
#pragma unroll
      for (int i = 0; i < 4; ++i)
#pragma unroll
        for (int j = 0; j < NJ; ++j)
          acc[4 + i][j] = __builtin_amdgcn_mfma_f32_16x16x32_bf16(afr[i][ks], bfr[j][ks], acc[4 + i][j], 0, 0, 0);
    __builtin_amdgcn_s_setprio(0);

    if (kt + 1 < nkt) {
      bar();                             // all waves done reading buf[cur]
      if (kt + 2 < nkt) {
        stage(kt + 2, cur);              // overwrite freed buffer
        vwait<LPT>();                    // tile kt+1 landed; kt+2 stays in flight
      } else {
        vwait<0>();                      // tail: drain
      }
      bar();                             // everyone's kt+1 loads landed
    }
    cur ^= 1;
  }

  // epilogue: C/D layout col=lane&15, row=(lane>>4)*4+r
#pragma unroll
  for (int i = 0; i < 8; ++i) {
    const int rbase = m0 + wr * 128 + i * 16 + ((lane >> 4) << 2);
#pragma unroll
    for (int j = 0; j < NJ; ++j) {
      const int cc = n0 + wc * WCN + j * 16 + (lane & 15);
      float bv = 0.f;
      if (BIAS) bv = bias[cc];
#pragma unroll
      for (int r = 0; r < 4; ++r) {
        const int row = rbase + r;
        float v = acc[i][j][r] + bv;
        if (EMB)  v = v * 32.f + pos[(size_t)(row & (SS - 1)) * N + cc];
        if (RELU) v = fmaxf(v, 0.f);
        if (RESID) v += resid[(size_t)row * N + cc];
        if (WF32)  outf[(size_t)row * N + cc] = v;
        if (WBF16) outb[(size_t)row * N + cc] = f2b(v);
      }
    }
  }
}

// ---------------- flash attention, swapped-QK^T in-register softmax ----------------
__global__ __launch_bounds__(256) void attn2(
    const unsigned short* __restrict__ qkv,   // [M][3072]: Q|K|V
    const unsigned short* __restrict__ vt,    // [bh][64][1024] = V^T per head
    unsigned short* __restrict__ O) {         // [M][1024]
  __shared__ __align__(1024) char smem[2 * 16384];   // dbuf x (K 8KB | VT 8KB)
  const int t = threadIdx.x, lane = t & 63, w = t >> 6;
  const int l31 = lane & 31, lg = lane >> 5;   // lane group (0/1)
  const int bh = blockIdx.y;
  const int b = bh >> 4, h = bh & 15;
  const size_t rowb = (size_t)b << 10;
  const int q0 = blockIdx.x * 128 + w * 32;

  bf16x8_t qf[4];
  {
    const unsigned short* Qp = qkv + (rowb + q0 + l31) * 3072 + h * 64 + lg * 8;
#pragma unroll
    for (int dd = 0; dd < 4; ++dd) qf[dd] = *(const bf16x8_t*)(Qp + dd * 16);
  }

  f32x16_t oa0, oa1;
#pragma unroll
  for (int r = 0; r < 16; ++r) { oa0[r] = 0.f; oa1[r] = 0.f; }
  float m_run = -1e30f, l_run = 0.f;
  const float inv32 = 1.f / 32.f;

  const char* kglob = (const char*)qkv + ((size_t)1024 + h * 64) * 2;
  const char* vglob = (const char*)vt + (size_t)bh * 64 * 1024 * 2;

  auto stage = [&](int kt, int buf) {
    char* kbuf = smem + buf * 16384;
    char* vbuf = kbuf + 8192;
#pragma unroll
    for (int i = 0; i < 2; ++i) {
      const int chunk = w * 2 + i;                 // 0..7
      const int byteoff = chunk * 1024 + lane * 16;
      const int row = byteoff >> 7;                // 0..63
      const int scb = (byteoff & 127) ^ ((row & 7) << 4);
      gload16(kglob + (size_t)(rowb + kt * 64 + row) * 6144 + scb, kbuf + chunk * 1024);
      gload16(vglob + ((size_t)row * 1024 + kt * 64) * 2 + scb,    vbuf + chunk * 1024);
    }
  };

  stage(0, 0);
  for (int kt = 0; kt < 16; ++kt) {
    const int cb = kt & 1;
    __syncthreads();
    if (kt < 15) stage(kt + 1, cb ^ 1);
    const char* kbuf = smem + cb * 16384;
    const char* vbuf = kbuf + 8192;

    f32x16_t p0, p1;
#pragma unroll
    for (int r = 0; r < 16; ++r) { p0[r] = 0.f; p1[r] = 0.f; }
    __builtin_amdgcn_s_setprio(1);
#pragma unroll
    for (int dd = 0; dd < 4; ++dd) {
      {
        const int row = l31;
        const int col = (dd * 32 + (lg << 4)) ^ ((row & 7) << 4);
        bf16x8_t kf = *(const bf16x8_t*)(kbuf + row * 128 + col);
        p0 = __builtin_amdgcn_mfma_f32_32x32x16_bf16(kf, qf[dd], p0, 0, 0, 0);
      }
      {
        const int row = 32 + l31;
        const int col = (dd * 32 + (lg << 4)) ^ ((row & 7) << 4);
        bf16x8_t kf = *(const bf16x8_t*)(kbuf + row * 128 + col);
        p1 = __builtin_amdgcn_mfma_f32_32x32x16_bf16(kf, qf[dd], p1, 0, 0, 0);
      }
    }
    __builtin_amdgcn_s_setprio(0);

    float mx = p0[0];
#pragma unroll
    for (int r = 1; r < 16; ++r) mx = fmaxf(mx, p0[r]);
#pragma unroll
    for (int r = 0; r < 16; ++r) mx = fmaxf(mx, p1[r]);
    mx = fmaxf(mx, __shfl_xor(mx, 32));
    const float mn = fmaxf(m_run, mx * inv32);
    const float fr = __expf(m_run - mn);
    m_run = mn;
    float sum = 0.f;
#pragma unroll
    for (int r = 0; r < 16; ++r) { const float e = __expf(p0[r] * inv32 - mn); p0[r] = e; sum += e; }
#pragma unroll
    for (int r = 0; r < 16; ++r) { const float e = __expf(p1[r] * inv32 - mn); p1[r] = e; sum += e; }
    sum += __shfl_xor(sum, 32);
    l_run = l_run * fr + sum;
#pragma unroll
    for (int r = 0; r < 16; ++r) { oa0[r] *= fr; oa1[r] *= fr; }

    const unsigned A0 = pkbf(p0[0], p0[1]),  B0 = pkbf(p0[2], p0[3]);
    const unsigned C0 = pkbf(p0[4], p0[5]),  D0 = pkbf(p0[6], p0[7]);
    const unsigned E0 = pkbf(p0[8], p0[9]),  F0 = pkbf(p0[10], p0[11]);
    const unsigned G0 = pkbf(p0[12], p0[13]), H0 = pkbf(p0[14], p0[15]);
    const unsigned A1 = pkbf(p1[0], p1[1]),  B1 = pkbf(p1[2], p1[3]);
    const unsigned C1 = pkbf(p1[4], p1[5]),  D1 = pkbf(p1[6], p1[7]);
    const unsigned E1 = pkbf(p1[8], p1[9]),  F1 = pkbf(p1[10], p1[11]);
    const unsigned G1 = pkbf(p1[12], p1[13]), H1 = pkbf(p1[14], p1[15]);
    const unsigned sA0 = __shfl_xor((int)A0, 32), sB0 = __shfl_xor((int)B0, 32);
    const unsigned sC0 = __shfl_xor((int)C0, 32), sD0 = __shfl_xor((int)D0, 32);
    const unsigned sE0 = __shfl_xor((int)E0, 32), sF0 = __shfl_xor((int)F0, 32);
    const unsigned sG0 = __shfl_xor((int)G0, 32), sH0 = __shfl_xor((int)H0, 32);
    const unsigned sA1 = __shfl_xor((int)A1, 32), sB1 = __shfl_xor((int)B1, 32);
    const unsigned sC1 = __shfl_xor((int)C1, 32), sD1 = __shfl_xor((int)D1, 32);
    const unsigned sE1 = __shfl_xor((int)E1, 32), sF1 = __shfl_xor((int)F1, 32);
    const unsigned sG1 = __shfl_xor((int)G1, 32), sH1 = __shfl_xor((int)H1, 32);
    const bool hi = (lg != 0);
    bf16x8_t pf[4];
    pf[0] = hi ? mk8(sC0, sD0, C0, D0) : mk8(A0, B0, sA0, sB0);
    pf[1] = hi ? mk8(sG0, sH0, G0, H0) : mk8(E0, F0, sE0, sF0);
    pf[2] = hi ? mk8(sC1, sD1, C1, D1) : mk8(A1, B1, sA1, sB1);
    pf[3] = hi ? mk8(sG1, sH1, G1, H1) : mk8(E1, F1, sE1, sF1);

    __builtin_amdgcn_s_setprio(1);
#pragma unroll
    for (int c = 0; c < 4; ++c) {
      {
        const int row = l31;
        const int col = (c * 32 + (lg << 4)) ^ ((row & 7) << 4);
        bf16x8_t vf = *(const bf16x8_t*)(vbuf + row * 128 + col);
        oa0 = __builtin_amdgcn_mfma_f32_32x32x16_bf16(vf, pf[c], oa0, 0, 0, 0);
      }
      {
        const int row = 32 + l31;
        const int col = (c * 32 + (lg << 4)) ^ ((row & 7) << 4);
        bf16x8_t vf = *(const bf16x8_t*)(vbuf + row * 128 + col);
        oa1 = __builtin_amdgcn_mfma_f32_32x32x16_bf16(vf, pf[c], oa1, 0, 0, 0);
      }
    }
    __builtin_amdgcn_s_setprio(0);
  }

  const float inv = 1.f / l_run;
  unsigned short* op = O + (rowb + q0 + l31) * 1024 + h * 64 + (lg << 2);
#pragma unroll
  for (int rg = 0; rg < 4; ++rg) {
    const unsigned u0 = pkbf(oa0[rg * 4 + 0] * inv, oa0[rg * 4 + 1] * inv);
    const unsigned u1 = pkbf(oa0[rg * 4 + 2] * inv, oa0[rg * 4 + 3] * inv);
    uint2 st = { u0, u1 };
    *(uint2*)(op + rg * 8) = st;
    const unsigned v0 = pkbf(oa1[rg * 4 + 0] * inv, oa1[rg * 4 + 1] * inv);
    const unsigned v1 = pkbf(oa1[rg * 4 + 2] * inv, oa1[rg * 4 + 3] * inv);
    uint2 st2 = { v0, v1 };
    *(uint2*)(op + 32 + rg * 8) = st2;
  }
}

// ---------------- LayerNorm: fp32 in -> fp32 + bf16 out ----------------
__global__ __launch_bounds__(256) void ln_kernel(
    const float* __restrict__ y, const float* __restrict__ g, const float* __restrict__ be,
    float* __restrict__ xf, unsigned short* __restrict__ xb) {
  const int row = blockIdx.x;
  const int t = threadIdx.x;
  const float4 v = ((const float4*)(y + (size_t)row * HDIM))[t];
  float s  = v.x + v.y + v.z + v.w;
  float ss = v.x*v.x + v.y*v.y + v.z*v.z + v.w*v.w;
#pragma unroll
  for (int m = 1; m < 64; m <<= 1) { s += __shfl_xor(s, m); ss += __shfl_xor(ss, m); }
  __shared__ float rs[4], rss[4];
  const int w = t >> 6, lane = t & 63;
  if (lane == 0) { rs[w] = s; rss[w] = ss; }
  __syncthreads();
  s  = rs[0] + rs[1] + rs[2] + rs[3];
  ss = rss[0] + rss[1] + rss[2] + rss[3];
  const float mean = s * (1.f / HDIM);
  const float inv = rsqrtf(ss * (1.f / HDIM) - mean * mean + 1e-5f);
  const int c = t * 4;
  const float4 gg = *(const float4*)(g + c);
  const float4 bb = *(const float4*)(be + c);
  float4 o;
  o.x = (v.x - mean) * inv * gg.x + bb.x;
  o.y = (v.y - mean) * inv * gg.y + bb.y;
  o.z = (v.z - mean) * inv * gg.z + bb.z;
  o.w = (v.w - mean) * inv * gg.w + bb.w;
  ((float4*)(xf + (size_t)row * HDIM))[t] = o;
  ushort4 ob = { f2b(o.x), f2b(o.y), f2b(o.z), f2b(o.w) };
  ((ushort4*)(xb + (size_t)row * HDIM))[t] = ob;
}

// ---------------- host ----------------
extern "C" void kernel_launch(void* const* d_in, const int* in_sizes, int n_in,
                              void* d_out, int out_size, void* d_ws, size_t ws_size,
                              hipStream_t stream) {
  const float* input_x = (const float*)d_in[0];
  const float* emb_W   = (const float*)d_in[1];
  const float* emb_b   = (const float*)d_in[2];
  const float* pos_tab = (const float*)d_in[3];
  const float* Wq  = (const float*)d_in[4];
  const float* bq  = (const float*)d_in[5];
  const float* Wk  = (const float*)d_in[6];
  const float* bk  = (const float*)d_in[7];
  const float* Wv  = (const float*)d_in[8];
  const float* bv  = (const float*)d_in[9];
  const float* Wo  = (const float*)d_in[10];
  const float* bo  = (const float*)d_in[11];
  const float* ln1g = (const float*)d_in[12];
  const float* ln1b = (const float*)d_in[13];
  const float* W1  = (const float*)d_in[14];
  const float* b1  = (const float*)d_in[15];
  const float* W2  = (const float*)d_in[16];
  const float* b2  = (const float*)d_in[17];
  const float* ln2g = (const float*)d_in[18];
  const float* ln2b = (const float*)d_in[19];
  float* out = (float*)d_out;

  char* ws = (char*)d_ws;
  size_t off = 0;
  auto alloc = [&](size_t bytes) {
    char* p = ws + off;
    off += (bytes + 255) & ~(size_t)255;
    return p;
  };
  unsigned short* wqkvT = (unsigned short*)alloc((size_t)3072 * HDIM * 2);
  unsigned short* woT   = (unsigned short*)alloc((size_t)HDIM * HDIM * 2);
  unsigned short* w1T   = (unsigned short*)alloc((size_t)PFF * HDIM * 2);   // [PF][H]
  unsigned short* w2T   = (unsigned short*)alloc((size_t)HDIM * PFF * 2);   // [H][PF]
  unsigned short* embWT = (unsigned short*)alloc((size_t)HDIM * 256 * 2);   // [H][IN]
  float*          bqkv  = (float*)alloc(3072 * 4);
  unsigned short* inb   = (unsigned short*)alloc((size_t)MM * 256 * 2);
  unsigned short* xb    = (unsigned short*)alloc((size_t)MM * HDIM * 2);
  unsigned short* qkvb  = (unsigned short*)alloc((size_t)MM * 3072 * 2);    // 48MB
  unsigned short* vtb   = (unsigned short*)alloc((size_t)MM * HDIM * 2);    // 16MB
  unsigned short* ab    = (unsigned short*)alloc((size_t)MM * HDIM * 2);
  float* y = (float*)alloc((size_t)MM * HDIM * 4);
  unsigned short* hb = qkvb;   // FFN hidden [M][4096] spans qkvb+vtb (dead by FFN1)

  const dim3 blk256(256);
  const dim3 blk512(512);
  const dim3 tblk(32, 8);

  // prep
  cvt_bf16<<<dim3(MM * 256 / 4 / 256), blk256, 0, stream>>>(input_x, inb, MM * 256 / 4);
  transpose_bf16<<<dim3(HDIM / 32, 256 / 32), tblk, 0, stream>>>(emb_W, embWT, 256, HDIM);

  // embedding: x = (input @ embW + b)*32 + pos   -> out(fp32) + xb(bf16)
  gemm256<128, true, false, false, true, true, true><<<dim3(HDIM / 128, MM / 256), blk512, 0, stream>>>(
      inb, embWT, emb_b, nullptr, pos_tab, out, xb, MM, HDIM, 256);

  for (int l = 0; l < NLAYER; ++l) {
    const size_t wofs = (size_t)l * HDIM * HDIM;
    transpose_bf16<<<dim3(32, 32), tblk, 0, stream>>>(Wq + wofs, wqkvT,               HDIM, HDIM);
    transpose_bf16<<<dim3(32, 32), tblk, 0, stream>>>(Wk + wofs, wqkvT + 1024 * 1024, HDIM, HDIM);
    transpose_bf16<<<dim3(32, 32), tblk, 0, stream>>>(Wv + wofs, wqkvT + 2048 * 1024, HDIM, HDIM);
    transpose_bf16<<<dim3(32, 32), tblk, 0, stream>>>(Wo + wofs, woT, HDIM, HDIM);
    transpose_bf16<<<dim3(PFF / 32, HDIM / 32), tblk, 0, stream>>>(
        W1 + (size_t)l * HDIM * PFF, w1T, HDIM, PFF);
    transpose_bf16<<<dim3(HDIM / 32, PFF / 32), tblk, 0, stream>>>(
        W2 + (size_t)l * PFF * HDIM, w2T, PFF, HDIM);
    concat_bias<<<dim3(12), blk256, 0, stream>>>(bq + l * HDIM, bk + l * HDIM, bv + l * HDIM, bqkv);

    // fused QKV GEMM -> qkvb [M][3072]
    gemm256<256, true, false, false, false, false, true><<<dim3(3072 / 256, MM / 256), blk512, 0, stream>>>(
        xb, wqkvT, bqkv, nullptr, nullptr, nullptr, qkvb, MM, 3072, HDIM);

    // V^T per head
    vtrans<<<dim3(32, 256), tblk, 0, stream>>>(qkvb, vtb);

    // attention
    attn2<<<dim3(SS / 128, BB * NHEAD), blk256, 0, stream>>>(qkvb, vtb, ab);

    // O-proj + residual (resid = fp32 x in `out`)
    gemm256<128, true, false, true, false, true, false><<<dim3(HDIM / 128, MM / 256), blk512, 0, stream>>>(
        ab, woT, bo + l * HDIM, out, nullptr, y, nullptr, MM, HDIM, HDIM);
    ln_kernel<<<dim3(MM), blk256, 0, stream>>>(y, ln1g + l * HDIM, ln1b + l * HDIM, out, xb);

    // FFN
    gemm256<256, true, true, false, false, false, true><<<dim3(PFF / 256, MM / 256), blk512, 0, stream>>>(
        xb, w1T, b1 + (size_t)l * PFF, nullptr, nullptr, nullptr, hb, MM, PFF, HDIM);
    gemm256<128, true, false, true, false, true, false><<<dim3(HDIM / 128, MM / 256), blk512, 0, stream>>>(
        hb, w2T, b2 + l * HDIM, out, nullptr, y, nullptr, MM, HDIM, PFF);
    ln_kernel<<<dim3(MM), blk256, 0, stream>>>(y, ln2g + l * HDIM, ln2b + l * HDIM, out, xb);
  }
  (void)in_sizes; (void)n_in; (void)out_size; (void)ws_size;
}